// Round 5
// baseline (820.528 us; speedup 1.0000x reference)
//
#include <hip/hip_runtime.h>

// Problem constants
#define T     4
#define WQ    75
#define C     640
#define HW    100
#define WAY   5
#define SHOT  5
#define SHW   500
#define SPAD  512
#define QPAD  128
#define CT    128
#define NT    5
#define NPAIR 15

// ws layout (bytes)
#define WS_COVB_OFF  0            // 20*15*16384*2 = 9,830,400 (bf16, fragment order)
#define WS_QTB_OFF   9830400      // 300*640*128*2 = 49,152,000
#define WS_QTBW_OFF  58982400     // 300*640*128*2 = 49,152,000
#define WS_STB_OFF   108134400    // 20*640*512*2  = 13,107,200

typedef __attribute__((ext_vector_type(8)))  short bfrag8;
typedef __attribute__((ext_vector_type(16))) float f32x16;

__device__ __forceinline__ unsigned short f2bf(float x) {
    unsigned int u = __float_as_uint(x);
    return (unsigned short)((u + 0x7fffu + ((u >> 16) & 1u)) >> 16);   // RNE
}
__device__ __forceinline__ float bflo(unsigned u) { return __uint_as_float(u << 16); }
__device__ __forceinline__ float bfhi(unsigned u) { return __uint_as_float(u & 0xffff0000u); }

__device__ __forceinline__ void pair_ij(int p, int& ti, int& tj) {
    int base = 0;
    #pragma unroll
    for (int a = 0; a < NT; ++a) {
        int cnt = NT - a;
        if (p < base + cnt) { ti = a; tj = a + (p - base); return; }
        base += cnt;
    }
    ti = 0; tj = 0;
}

__global__ void init_out_kernel(float* __restrict__ out, const float* __restrict__ bias) {
    int i = blockIdx.x * blockDim.x + threadIdx.x;
    if (i < T * WQ * WAY) out[i] = bias[0];
}

// Fused mean + center + bf16 pack. Blocks 0..749: qtb/qtbw rows; 750..799: stb rows.
__global__ void meanpack_kernel(const float* __restrict__ qf, const float* __restrict__ sf,
                                const float* __restrict__ convw,
                                unsigned short* __restrict__ qtb, unsigned short* __restrict__ qtbw,
                                unsigned short* __restrict__ stb) {
    __shared__ float wl[HW];
    int tid = threadIdx.x;
    if (tid < HW) wl[tid] = convw[tid];
    __syncthreads();
    long long i = (long long)blockIdx.x * 256 + tid;
    if (i < (long long)T * WQ * C) {
        size_t r = (size_t)i;                       // tq*C + c
        const float4* p = (const float4*)(qf + r * HW);
        float accm = 0.f; float4 buf[25];
        #pragma unroll
        for (int f = 0; f < 25; ++f) { float4 v = p[f]; buf[f] = v; accm += v.x + v.y + v.z + v.w; }
        float m = accm * (1.0f / HW);
        const float* bs = (const float*)buf;
        #pragma unroll
        for (int oct = 0; oct < QPAD / 8; ++oct) {
            unsigned short ob[8] __attribute__((aligned(16)));
            unsigned short ow[8] __attribute__((aligned(16)));
            #pragma unroll
            for (int j = 0; j < 8; ++j) {
                int n = oct * 8 + j;
                float v = (n < HW) ? (bs[n] - m) : 0.f;
                float w = (n < HW) ? wl[n] : 0.f;
                ob[j] = f2bf(v); ow[j] = f2bf(v * w);
            }
            *(uint4*)(qtb  + r * QPAD + oct * 8) = *(uint4*)ob;
            *(uint4*)(qtbw + r * QPAD + oct * 8) = *(uint4*)ow;
        }
    } else if (i < (long long)T * WQ * C + (long long)T * WAY * C) {
        int j = (int)(i - (long long)T * WQ * C);   // tw*C + c
        int tw = j / C, c = j % C;
        float accm = 0.f;
        #pragma unroll
        for (int sh = 0; sh < SHOT; ++sh) {
            const float4* p = (const float4*)(sf + ((size_t)(tw * SHOT + sh) * C + c) * HW);
            #pragma unroll
            for (int f = 0; f < 25; ++f) { float4 v = p[f]; accm += v.x + v.y + v.z + v.w; }
        }
        float m = accm * (1.0f / SHW);
        for (int oct = 0; oct < SPAD / 8; ++oct) {
            unsigned short ob[8] __attribute__((aligned(16)));
            #pragma unroll
            for (int j2 = 0; j2 < 8; ++j2) {
                int mm = oct * 8 + j2; float v = 0.f;
                if (mm < SHW) {
                    int sh = mm / HW, n = mm % HW;
                    v = sf[((size_t)(tw * SHOT + sh) * C + c) * HW + n] - m;
                }
                ob[j2] = f2bf(v);
            }
            *(uint4*)(stb + (size_t)j * SPAD + oct * 8) = *(uint4*)ob;
        }
    }
}

// ---- shared staging / MFMA helpers (identical in cov & score => layout cancels) ----
// LDS plane: 128 rows x 32 k bf16, octet slot XOR-swizzled: slot = h8 ^ (row & 3)
__device__ __forceinline__ void stage_plane(unsigned short* dst, const unsigned short* src,
                                            int rowlen, int ch, int tid) {
    #pragma unroll
    for (int ii = 0; ii < 2; ++ii) {
        int u = tid + ii * 256;
        int c = u >> 2, h8 = u & 3;
        *(uint4*)&dst[(size_t)(c * 4 + (h8 ^ (c & 3))) * 8] =
            *(const uint4*)(src + (size_t)c * rowlen + ch * 32 + h8 * 8);
    }
}

__device__ __forceinline__ void mfma_chunk(const unsigned short* Al, const unsigned short* Bl,
                                           f32x16* acc, int mA, int nB, int x3, int lh) {
    #pragma unroll
    for (int s = 0; s < 2; ++s) {
        int sw = (((s * 2) + lh) ^ x3) * 8;
        bfrag8 a0 = *(const bfrag8*)&Al[(size_t)mA * 8 + sw];
        bfrag8 a1 = *(const bfrag8*)&Al[(size_t)(mA + 128) * 8 + sw];
        bfrag8 b0 = *(const bfrag8*)&Bl[(size_t)nB * 8 + sw];
        bfrag8 b1 = *(const bfrag8*)&Bl[(size_t)(nB + 128) * 8 + sw];
        acc[0] = __builtin_amdgcn_mfma_f32_32x32x16_bf16(a0, b0, acc[0], 0, 0, 0);
        acc[1] = __builtin_amdgcn_mfma_f32_32x32x16_bf16(a0, b1, acc[1], 0, 0, 0);
        acc[2] = __builtin_amdgcn_mfma_f32_32x32x16_bf16(a1, b0, acc[2], 0, 0, 0);
        acc[3] = __builtin_amdgcn_mfma_f32_32x32x16_bf16(a1, b1, acc[3], 0, 0, 0);
    }
}

// Cov tiles -> bf16 in fragment order. grid = (NPAIR, T*WAY)
__global__ __launch_bounds__(256, 2)
void cov_kernel(const unsigned short* __restrict__ stb, unsigned short* __restrict__ covb) {
    __shared__ unsigned short Al[4096], Bl[4096];
    int p = blockIdx.x, tw = blockIdx.y;
    int ti, tj; pair_ij(p, ti, tj);
    int tid = threadIdx.x, lane = tid & 63, wave = tid >> 6;
    int qm = wave & 1, qn = wave >> 1, lh = lane >> 5, ls = lane & 31;
    int mA = (qm * 64 + ls) * 4, nB = (qn * 64 + ls) * 4, x3 = ls & 3;
    const unsigned short* Ab = stb + ((size_t)tw * C + ti * CT) * SPAD;
    const unsigned short* Bb = stb + ((size_t)tw * C + tj * CT) * SPAD;

    f32x16 acc[4];
    #pragma unroll
    for (int b = 0; b < 4; ++b)
        #pragma unroll
        for (int e = 0; e < 16; ++e) acc[b][e] = 0.f;

    for (int ch = 0; ch < SPAD / 32; ++ch) {
        __syncthreads();
        stage_plane(Al, Ab, SPAD, ch, tid);
        stage_plane(Bl, Bb, SPAD, ch, tid);
        __syncthreads();
        mfma_chunk(Al, Bl, acc, mA, nB, x3, lh);
    }

    const float inv = 1.0f / (HW - 1);
    unsigned short* cb = covb + ((size_t)tw * NPAIR + p) * 16384;
    #pragma unroll
    for (int b = 0; b < 4; ++b) {
        unsigned ow[8];
        #pragma unroll
        for (int wd = 0; wd < 8; ++wd)
            ow[wd] = (unsigned)f2bf(acc[b][2 * wd] * inv)
                   | ((unsigned)f2bf(acc[b][2 * wd + 1] * inv) << 16);
        size_t off = (size_t)((wave * 4 + b) * 64 + lane) * 16;
        *(uint4*)(cb + off)     = *(uint4*)&ow[0];
        *(uint4*)(cb + off + 8) = *(uint4*)&ow[4];
    }
}

// Fused M-build (MFMA, 2 queries in flight) + bf16 cov Frobenius dot.
// grid = (qg=15, p=15, t=4): same-(p,t) blocks dispatch-consecutive for L2 reuse.
__global__ __launch_bounds__(256, 2)
void score_kernel(const unsigned short* __restrict__ qtb, const unsigned short* __restrict__ qtbw,
                  const unsigned short* __restrict__ covb, float* __restrict__ out) {
    __shared__ unsigned short Al0[4096], Bl0[4096], Al1[4096], Bl1[4096];
    __shared__ float red[4][10];
    int qg = blockIdx.x, p = blockIdx.y, t = blockIdx.z;
    int ti, tj; pair_ij(p, ti, tj);
    int tid = threadIdx.x, lane = tid & 63, wave = tid >> 6;
    int qm = wave & 1, qn = wave >> 1, lh = lane >> 5, ls = lane & 31;
    int mA = (qm * 64 + ls) * 4, nB = (qn * 64 + ls) * 4, x3 = ls & 3;
    float mult = (ti == tj) ? 1.0f : 2.0f;
    const unsigned short* cbase = covb + ((size_t)(t * WAY) * NPAIR + p) * 16384;

    for (int g = 0; g < 3; ++g) {
        int nq = (g == 2) ? 1 : 2;
        int q0 = qg * 5 + g * 2;
        const unsigned short* A0 = qtbw + ((size_t)(t * WQ + q0) * C + ti * CT) * QPAD;
        const unsigned short* B0 = qtb  + ((size_t)(t * WQ + q0) * C + tj * CT) * QPAD;
        const unsigned short* A1 = A0 + (size_t)C * QPAD;
        const unsigned short* B1 = B0 + (size_t)C * QPAD;

        f32x16 acc[8];
        #pragma unroll
        for (int b = 0; b < 8; ++b)
            #pragma unroll
            for (int e = 0; e < 16; ++e) acc[b][e] = 0.f;

        for (int ch = 0; ch < QPAD / 32; ++ch) {
            __syncthreads();                     // also protects red[] across groups
            stage_plane(Al0, A0, QPAD, ch, tid);
            stage_plane(Bl0, B0, QPAD, ch, tid);
            if (nq == 2) {
                stage_plane(Al1, A1, QPAD, ch, tid);
                stage_plane(Bl1, B1, QPAD, ch, tid);
            }
            __syncthreads();
            mfma_chunk(Al0, Bl0, acc, mA, nB, x3, lh);
            if (nq == 2) mfma_chunk(Al1, Bl1, acc + 4, mA, nB, x3, lh);
        }

        // bf16 cov dot: one cov read feeds both queries' M tiles
        float sums[2][WAY];
        #pragma unroll
        for (int w = 0; w < WAY; ++w) {
            const unsigned short* cb = cbase + (size_t)w * NPAIR * 16384;
            float s0 = 0.f, s1 = 0.f;
            #pragma unroll
            for (int b = 0; b < 4; ++b) {
                size_t off = (size_t)((wave * 4 + b) * 64 + lane) * 16;
                uint4 u0 = *(const uint4*)(cb + off);
                uint4 u1 = *(const uint4*)(cb + off + 8);
                unsigned uw[8] = {u0.x, u0.y, u0.z, u0.w, u1.x, u1.y, u1.z, u1.w};
                #pragma unroll
                for (int wd = 0; wd < 8; ++wd) {
                    float clo = bflo(uw[wd]), chi = bfhi(uw[wd]);
                    s0 += clo * acc[b][2 * wd] + chi * acc[b][2 * wd + 1];
                    if (nq == 2) s1 += clo * acc[4 + b][2 * wd] + chi * acc[4 + b][2 * wd + 1];
                }
            }
            sums[0][w] = s0 * mult; sums[1][w] = s1 * mult;
        }

        #pragma unroll
        for (int qi = 0; qi < 2; ++qi) {
            if (qi >= nq) break;
            #pragma unroll
            for (int w = 0; w < WAY; ++w) {
                float v = sums[qi][w];
                #pragma unroll
                for (int off = 32; off > 0; off >>= 1) v += __shfl_down(v, off);
                if (lane == 0) red[wave][qi * WAY + w] = v;
            }
        }
        __syncthreads();
        if (tid < nq * WAY) {
            int qi = tid / WAY, w = tid % WAY;
            float tot = red[0][tid] + red[1][tid] + red[2][tid] + red[3][tid];
            atomicAdd(&out[(size_t)(t * WQ + q0 + qi) * WAY + w], tot);
        }
    }
}

extern "C" void kernel_launch(void* const* d_in, const int* in_sizes, int n_in,
                              void* d_out, int out_size, void* d_ws, size_t ws_size,
                              hipStream_t stream) {
    const float* qf = (const float*)d_in[0];   // (4,75,640,10,10)
    const float* sf = (const float*)d_in[1];   // (4,25,640,10,10)
    const float* cw = (const float*)d_in[2];   // (1,1,100)
    const float* cb = (const float*)d_in[3];   // (1,)
    float* out = (float*)d_out;                // (4,75,5)

    unsigned short* covb = (unsigned short*)((char*)d_ws + WS_COVB_OFF);
    unsigned short* qtb  = (unsigned short*)((char*)d_ws + WS_QTB_OFF);
    unsigned short* qtbw = (unsigned short*)((char*)d_ws + WS_QTBW_OFF);
    unsigned short* stb  = (unsigned short*)((char*)d_ws + WS_STB_OFF);

    init_out_kernel<<<(T * WQ * WAY + 255) / 256, 256, 0, stream>>>(out, cb);
    meanpack_kernel<<<800, 256, 0, stream>>>(qf, sf, cw, qtb, qtbw, stb);
    cov_kernel<<<dim3(NPAIR, T * WAY), 256, 0, stream>>>(stb, covb);
    score_kernel<<<dim3(WQ / 5, NPAIR, T), 256, 0, stream>>>(qtb, qtbw, covb, out);
}